// Round 1
// baseline (699.008 us; speedup 1.0000x reference)
//
#include <hip/hip_runtime.h>
#include <hip/hip_bf16.h>
#include <stdint.h>

// ---------------------------------------------------------------------------
// Mlp_cnn_shift: B=2 T=8 H=56 W=56 C=512 HID=1024, N = 50176 tokens
//  xb   = bf16(x)                                   [N,512]
//  GEMM1: xh = gelu(xb@fc_w+b); dual-store: xh + forward-shift scatter -> xs
//  GEMM2: hs = inverse-shift scatter of gelu(xs@fc1_w+b); fused s0 sum
//  GEMM3: w  = gelu(xh@fc2_w+b); fused s1 sum
//  tiny MLP + pairwise softmax -> a0,a1 (fp32 exact)
//  combine: hw = hs*a0 + w*a1 (shift-free, 16B vectorized)
//  GEMM4: out = hw @ proj_w + proj_b (fp32)
// Shift boundary holes pre-zeroed by zero_holes (3.5% strips).
//
// R1 changes vs baseline:
//  * K-loop: double-buffered LDS, STAGE(t+1) issued BEFORE ds_read+MFMA(t),
//    single __syncthreads per tile (T3-minimum pipeline; loads overlap MFMA).
//  * Epilogue: operand-swapped MFMA (D transposed) -> each lane owns 4
//    consecutive channels -> packed uint2/float4 stores, float4 bias load,
//    pack-uniform shift fast path, shfl-over-token fused sums.
// ---------------------------------------------------------------------------

typedef __attribute__((ext_vector_type(8))) short short8;
typedef __attribute__((ext_vector_type(4))) float floatx4;
typedef unsigned int uint;
typedef unsigned short ushort;

#define NTOK   50176
#define HWIMG  3136    // 56*56

// exact gelu (tiny MLP only)
__device__ __forceinline__ float gelu_exact(float v) {
    return 0.5f * v * (1.0f + erff(v * 0.70710678118654752440f));
}
// tanh-approx gelu = v * sigmoid(2u), u = 0.79788456*(v + 0.044715 v^3)
__device__ __forceinline__ float gelu_fast(float v) {
    float u = v * (0.7978845608f + 0.0356774081f * v * v);
    return v * __builtin_amdgcn_rcpf(1.0f + __expf(-2.0f * u));
}

// shifts: g in 0..8 -> (1-g/3, 1-g%3) matches SHIFTS table
__device__ __forceinline__ int shift_h(int g) { return 1 - g / 3; }
__device__ __forceinline__ int shift_w(int g) { return 1 - g % 3; }

__device__ __forceinline__ uint pack_bf2(float lo, float hi) {
    __hip_bfloat16 a = __float2bfloat16(lo), b = __float2bfloat16(hi);
    return (uint)*(ushort*)&a | ((uint)*(ushort*)&b << 16);
}

// ---- async global->LDS, 16B per lane ---------------------------------------
typedef const __attribute__((address_space(1))) uint* gas_ptr;
typedef __attribute__((address_space(3))) uint* las_ptr;

__device__ __forceinline__ void async_copy16(const void* g, void* l) {
    gas_ptr gp = (gas_ptr)(uintptr_t)g;
    las_ptr lp = (las_ptr)(uint32_t)(uintptr_t)l;
    __builtin_amdgcn_global_load_lds(gp, lp, 16, 0, 0);
}

// ---- GEMM: C[M,N] = act(A[M,K] @ Bt[N,K]^T + bias) -------------------------
// BM=BN=128, BK=32, 256 thr = 4 waves (2x2), wave 64x64 via 4x4 mfma 16x16x32.
// Operand-swapped: D-row = channel ((lane>>4)*4+reg), D-col = token (lane&15).
// EPI: 0 = fp32 float4 store (GEMM4)
//      1 = gelu bf16 uint2 store + forward-shift scatter to Cout2 (GEMM1)
//      2 = gelu bf16 inverse-shift scatter ONLY + fused sum -> ssum (GEMM2)
//      3 = gelu bf16 uint2 store + fused sum -> ssum (GEMM3)
template <int EPI>
__global__ __launch_bounds__(256) void gemm_bt(
    const __hip_bfloat16* __restrict__ A,
    const __hip_bfloat16* __restrict__ Bt,
    const float* __restrict__ bias,
    void* __restrict__ Cout, __hip_bfloat16* __restrict__ Cout2,
    float* __restrict__ ssum, int N, int K)
{
    __shared__ __align__(16) __hip_bfloat16 As[2][128 * 32];
    __shared__ __align__(16) __hip_bfloat16 Bs[2][128 * 32];

    const int t    = threadIdx.x;
    const int lane = t & 63;
    const int wave = t >> 6;
    const int wm   = wave >> 1;
    const int wn   = wave & 1;

    // XCD swizzle: round-robin dispatch puts flat%8 on XCD flat&7; give each
    // XCD a contiguous bm range so its private L2 keeps the A-tiles.
    const int nbn  = gridDim.x;
    const int flat = blockIdx.y * nbn + blockIdx.x;
    const int xcd  = flat & 7;
    const int j    = flat >> 3;
    const int jd   = j / nbn;
    const int bm   = xcd * 49 + jd;
    const int bn   = j - jd * nbn;

    const __hip_bfloat16* ga0 = A  + (size_t)(bm * 128 + (t >> 2)) * K + (t & 3) * 8;
    const __hip_bfloat16* ga1 = ga0 + (size_t)64 * K;
    const __hip_bfloat16* gb0 = Bt + (size_t)(bn * 128 + (t >> 2)) * K + (t & 3) * 8;
    const __hip_bfloat16* gb1 = gb0 + (size_t)64 * K;
    const int t8 = t * 8;

    floatx4 acc[4][4] = {};
    const int kq = (lane >> 4) * 8;
    const int ml = lane & 15;

    auto stage = [&](int buf) {
        async_copy16(ga0, &As[buf][t8]);
        async_copy16(ga1, &As[buf][t8 + 2048]);
        async_copy16(gb0, &Bs[buf][t8]);
        async_copy16(gb1, &Bs[buf][t8 + 2048]);
        ga0 += 32; ga1 += 32; gb0 += 32; gb1 += 32;
    };

    const int nt = K >> 5;
    stage(0);
    __syncthreads();                     // vmcnt(0) drain: tile 0 ready

    for (int tt = 0; tt < nt; ++tt) {
        const int cur = tt & 1;
        if (tt + 1 < nt) stage(cur ^ 1); // overlap next-tile loads with compute

        short8 af[4], bf[4];
#pragma unroll
        for (int i = 0; i < 4; i++) {
            af[i] = *(const short8*)&As[cur][(wm * 64 + i * 16 + ml) * 32 + kq];
            bf[i] = *(const short8*)&Bs[cur][(wn * 64 + i * 16 + ml) * 32 + kq];
        }
#pragma unroll
        for (int mi = 0; mi < 4; mi++)
#pragma unroll
            for (int ni = 0; ni < 4; ni++)
                acc[mi][ni] = __builtin_amdgcn_mfma_f32_16x16x32_bf16(
                    bf[ni], af[mi], acc[mi][ni], 0, 0, 0);  // SWAPPED operands

        __syncthreads();                 // drains vmcnt(0): tile tt+1 landed,
                                         // all reads of buf[cur] retired
    }

    // ---- epilogue (transposed D): channel = chb+ni*16+r, token = tkb+mi*16 -
    const int rq  = (lane >> 4) * 4;
    const int chb = bn * 128 + wn * 64 + rq;
    const int tkb = bm * 128 + wm * 64 + ml;

    float s_ac[4][4];
    if (EPI == 2 || EPI == 3)
#pragma unroll
        for (int ni = 0; ni < 4; ni++)
#pragma unroll
            for (int r = 0; r < 4; r++) s_ac[ni][r] = 0.f;

#pragma unroll
    for (int ni = 0; ni < 4; ni++) {
        const int ch0 = chb + ni * 16;
        const float4 b4 = *(const float4*)&bias[ch0];
        int gsh = 0, gsw = 0;
        bool guni = true;
        if (EPI == 1 || EPI == 2) {
            const int DIV = (EPI == 1) ? 114 : 57;
            const int g0 = ch0 / DIV, g3 = (ch0 + 3) / DIV;
            guni = (g0 == g3);
            gsh = shift_h(g0); gsw = shift_w(g0);
        }
#pragma unroll
        for (int mi = 0; mi < 4; mi++) {
            const int tok = tkb + mi * 16;
            float v[4];
            v[0] = acc[mi][ni][0] + b4.x;
            v[1] = acc[mi][ni][1] + b4.y;
            v[2] = acc[mi][ni][2] + b4.z;
            v[3] = acc[mi][ni][3] + b4.w;
            if (EPI != 0) {
#pragma unroll
                for (int r = 0; r < 4; r++) v[r] = gelu_fast(v[r]);
            }

            if (EPI == 0) {
                float4 o; o.x = v[0]; o.y = v[1]; o.z = v[2]; o.w = v[3];
                *(float4*)&((float*)Cout)[(size_t)tok * N + ch0] = o;
            } else {
                uint2 u;
                u.x = pack_bf2(v[0], v[1]);
                u.y = pack_bf2(v[2], v[3]);

                if (EPI == 1 || EPI == 3)
                    *(uint2*)&((__hip_bfloat16*)Cout)[(size_t)tok * N + ch0] = u;

                if (EPI == 1 || EPI == 2) {
                    const int rem = tok - (tok / HWIMG) * HWIMG;
                    const int ph = rem / 56, pw = rem - ph * 56;
                    if (EPI == 1) {
                        if (guni) {
                            if ((unsigned)(ph + gsh) < 56u && (unsigned)(pw + gsw) < 56u)
                                *(uint2*)&Cout2[(size_t)(tok + gsh * 56 + gsw) * N + ch0] = u;
                        } else {
#pragma unroll
                            for (int r = 0; r < 4; r++) {
                                const int g = (ch0 + r) / 114;
                                const int sh = shift_h(g), sw = shift_w(g);
                                if ((unsigned)(ph + sh) < 56u && (unsigned)(pw + sw) < 56u)
                                    Cout2[(size_t)(tok + sh * 56 + sw) * N + ch0 + r]
                                        = __float2bfloat16(v[r]);
                            }
                        }
                    } else {  // EPI == 2, inverse shift
                        if (guni) {
                            if ((unsigned)(ph - gsh) < 56u && (unsigned)(pw - gsw) < 56u) {
                                *(uint2*)&((__hip_bfloat16*)Cout)
                                    [(size_t)(tok - gsh * 56 - gsw) * N + ch0] = u;
#pragma unroll
                                for (int r = 0; r < 4; r++) s_ac[ni][r] += v[r];
                            }
                        } else {
#pragma unroll
                            for (int r = 0; r < 4; r++) {
                                const int g = (ch0 + r) / 57;
                                const int sh = shift_h(g), sw = shift_w(g);
                                if ((unsigned)(ph - sh) < 56u && (unsigned)(pw - sw) < 56u) {
                                    ((__hip_bfloat16*)Cout)
                                        [(size_t)(tok - sh * 56 - sw) * N + ch0 + r]
                                        = __float2bfloat16(v[r]);
                                    s_ac[ni][r] += v[r];
                                }
                            }
                        }
                    }
                }
                if (EPI == 3) {
#pragma unroll
                    for (int r = 0; r < 4; r++) s_ac[ni][r] += v[r];
                }
            }
        }
    }

    if (EPI == 2 || EPI == 3) {
        const int b = (bm >= 196) ? 1 : 0;   // token 25088 = block 196 boundary
#pragma unroll
        for (int ni = 0; ni < 4; ni++)
#pragma unroll
            for (int r = 0; r < 4; r++) {
                float s = s_ac[ni][r];
                s += __shfl_xor(s, 1, 64);
                s += __shfl_xor(s, 2, 64);
                s += __shfl_xor(s, 4, 64);
                s += __shfl_xor(s, 8, 64);
                if (ml == 0) atomicAdd(&ssum[b * 512 + chb + ni * 16 + r], s);
            }
    }
}

// ---- zero the shift boundary holes (frame strips only, ~3.5%) --------------
template <int C, int GS, int SGN>
__global__ __launch_bounds__(256) void zero_holes(__hip_bfloat16* __restrict__ buf)
{
    const int i = blockIdx.x * 256 + threadIdx.x;   // 16*220*C exact
    const int c = i % C;
    const int p = i / C;
    const int bt = p / 220, fp = p % 220;
    int oh, ow;
    if (fp < 56)       { oh = 0;        ow = fp; }
    else if (fp < 112) { oh = 55;       ow = fp - 56; }
    else if (fp < 166) { oh = fp - 111; ow = 0; }
    else               { oh = fp - 165; ow = 55; }
    const int g = c / GS;
    const int ih = oh - SGN * shift_h(g);
    const int iw = ow - SGN * shift_w(g);
    if ((unsigned)ih >= 56u || (unsigned)iw >= 56u)
        buf[((size_t)(bt * HWIMG + oh * 56 + ow)) * C + c] = __float2bfloat16(0.0f);
}

// ---- prep: x fp32 -> bf16 ---------------------------------------------------
__global__ __launch_bounds__(256) void cvt_x(const float4* __restrict__ x,
                                             __hip_bfloat16* __restrict__ xb)
{
    int i = blockIdx.x * 256 + threadIdx.x;
    float4 v = x[i];
    __hip_bfloat16 b0 = __float2bfloat16(v.x);
    __hip_bfloat16 b1 = __float2bfloat16(v.y);
    __hip_bfloat16 b2 = __float2bfloat16(v.z);
    __hip_bfloat16 b3 = __float2bfloat16(v.w);
    uint2 o;
    o.x = (uint)*(ushort*)&b0 | ((uint)*(ushort*)&b1 << 16);
    o.y = (uint)*(ushort*)&b2 | ((uint)*(ushort*)&b3 << 16);
    *(uint2*)&xb[(size_t)i * 4] = o;
}

// ---- prep: transpose + convert the 4 weight matrices to bf16 Bt layout -----
__global__ __launch_bounds__(256) void prep_w(
    const float* __restrict__ fcw,  const float* __restrict__ fc1w,
    const float* __restrict__ fc2w, const float* __restrict__ projw,
    __hip_bfloat16* __restrict__ fcwT, __hip_bfloat16* __restrict__ fc1T,
    __hip_bfloat16* __restrict__ fc2T, __hip_bfloat16* __restrict__ projT)
{
    int i = blockIdx.x * 256 + threadIdx.x;
    if (i < 524288) {                       // fc_w [512,1024] -> [1024,512]
        int n = i >> 9, k = i & 511;
        fcwT[i] = __float2bfloat16(fcw[k * 1024 + n]);
    } else if (i < 1048576) {               // fc1_w [1024,512] -> [512,1024]
        int j = i - 524288;
        int n = j >> 10, k = j & 1023;
        fc1T[j] = __float2bfloat16(fc1w[k * 512 + n]);
    } else if (i < 1572864) {               // fc2_w [1024,512] -> [512,1024]
        int j = i - 1048576;
        int n = j >> 10, k = j & 1023;
        fc2T[j] = __float2bfloat16(fc2w[k * 512 + n]);
    } else if (i < 1835008) {               // proj_w [512,512] -> [512,512]
        int j = i - 1572864;
        int n = j >> 9, k = j & 511;
        projT[j] = __float2bfloat16(projw[k * 512 + n]);
    }
}

// ---- tiny squeeze-excite MLP + pairwise softmax, fp32 exact ----------------
__global__ __launch_bounds__(256) void tiny_mlp(
    const float* __restrict__ s0, const float* __restrict__ s1,
    const float* __restrict__ rw1_w, const float* __restrict__ rw1_b,
    const float* __restrict__ rw2_w, const float* __restrict__ rw2_b,
    float* __restrict__ a0, float* __restrict__ a1)
{
    __shared__ float mean[1024];   // [2][512]
    __shared__ float z[256];       // [2][128]
    __shared__ float av[2048];     // [2][1024]
    const int t = threadIdx.x;
    for (int i = t; i < 1024; i += 256)
        mean[i] = (s0[i] + s1[i]) * (1.0f / 25088.0f);
    __syncthreads();
    {
        const int b = t >> 7, j = t & 127;
        float acc = rw1_b[j];
        for (int cc = 0; cc < 512; cc++)
            acc += mean[b * 512 + cc] * rw1_w[cc * 128 + j];
        z[t] = gelu_exact(acc);
    }
    __syncthreads();
    for (int i = t; i < 2048; i += 256) {
        const int b = i >> 10, o = i & 1023;
        float acc = rw2_b[o];
        for (int j = 0; j < 128; j++)
            acc += z[b * 128 + j] * rw2_w[j * 1024 + o];
        av[i] = acc;
    }
    __syncthreads();
    for (int i = t; i < 1024; i += 256) {
        const int b = i >> 9, cc = i & 511;
        const float x0 = av[b * 1024 + 2 * cc];
        const float x1 = av[b * 1024 + 2 * cc + 1];
        const float m = fmaxf(x0, x1);
        const float e0 = expf(x0 - m), e1 = expf(x1 - m);
        const float inv = 1.0f / (e0 + e1);
        a0[i] = e0 * inv;
        a1[i] = e1 * inv;
    }
}

// ---- hw = hs*a0 + w*a1 (shift-free, 8 channels / thread) --------------------
__device__ __forceinline__ float bf_lo(uint u) { return __uint_as_float(u << 16); }
__device__ __forceinline__ float bf_hi(uint u) { return __uint_as_float(u & 0xffff0000u); }

__global__ __launch_bounds__(256) void combine(
    const uint4* __restrict__ hs4, const uint4* __restrict__ w4,
    const float* __restrict__ a0, const float* __restrict__ a1,
    uint4* __restrict__ hw4)
{
    const int i = blockIdx.x * 256 + threadIdx.x;   // 3,211,264 exact
    const int ck = i & 63;                          // 8-channel chunk
    const int tok = i >> 6;
    const int b = (tok >= 25088) ? 1 : 0;
    const float4* A0 = (const float4*)&a0[b * 512 + ck * 8];
    const float4* A1 = (const float4*)&a1[b * 512 + ck * 8];
    const float4 s0l = A0[0], s0h = A0[1];
    const float4 s1l = A1[0], s1h = A1[1];
    const uint4 h = hs4[i], w = w4[i];
    uint4 o;
    o.x = pack_bf2(bf_lo(h.x) * s0l.x + bf_lo(w.x) * s1l.x,
                   bf_hi(h.x) * s0l.y + bf_hi(w.x) * s1l.y);
    o.y = pack_bf2(bf_lo(h.y) * s0l.z + bf_lo(w.y) * s1l.z,
                   bf_hi(h.y) * s0l.w + bf_hi(w.y) * s1l.w);
    o.z = pack_bf2(bf_lo(h.z) * s0h.x + bf_lo(w.z) * s1h.x,
                   bf_hi(h.z) * s0h.y + bf_hi(w.z) * s1h.y);
    o.w = pack_bf2(bf_lo(h.w) * s0h.z + bf_lo(w.w) * s1h.z,
                   bf_hi(h.w) * s0h.w + bf_hi(w.w) * s1h.w);
    hw4[i] = o;
}

// ---------------------------------------------------------------------------
extern "C" void kernel_launch(void* const* d_in, const int* in_sizes, int n_in,
                              void* d_out, int out_size, void* d_ws, size_t ws_size,
                              hipStream_t stream)
{
    const float* x      = (const float*)d_in[0];
    const float* fc_w   = (const float*)d_in[1];
    const float* fc_b   = (const float*)d_in[2];
    const float* fc1_w  = (const float*)d_in[3];
    const float* fc1_b  = (const float*)d_in[4];
    const float* fc2_w  = (const float*)d_in[5];
    const float* fc2_b  = (const float*)d_in[6];
    const float* rw1_w  = (const float*)d_in[7];
    const float* rw1_b  = (const float*)d_in[8];
    const float* rw2_w  = (const float*)d_in[9];
    const float* rw2_b  = (const float*)d_in[10];
    const float* proj_w = (const float*)d_in[11];
    const float* proj_b = (const float*)d_in[12];

    uint8_t* ws = (uint8_t*)d_ws;
    __hip_bfloat16* xh  = (__hip_bfloat16*)(ws);                    // [N,1024] bf16, later hw
    __hip_bfloat16* xb  = (__hip_bfloat16*)(ws + 102760448);        // [N,512] bf16, later hs
    uint8_t* wt         = ws + 102760448 + 51380224;
    __hip_bfloat16* fcwT  = (__hip_bfloat16*)(wt);
    __hip_bfloat16* fc1T  = fcwT + 524288;
    __hip_bfloat16* fc2T  = fc1T + 524288;
    __hip_bfloat16* projT = fc2T + 524288;
    float* s0 = (float*)(wt + 3670016);
    float* s1 = s0 + 1024;
    float* a0 = s1 + 1024;
    float* a1 = a0 + 1024;

    __hip_bfloat16* xs   = (__hip_bfloat16*)d_out;  // [N,1024] bf16 (dead after GEMM2)
    __hip_bfloat16* wbuf = (__hip_bfloat16*)d_out;  // [N,512]  bf16 (dead after combine)
    __hip_bfloat16* hs   = xb;                      // [N,512]  bf16 (xb dead after GEMM1)
    __hip_bfloat16* hw   = xh;                      // [N,512]  bf16 (xh dead after GEMM3)

    hipMemsetAsync(s0, 0, 8192, stream);            // zero s0,s1

    // xs boundary holes (d_out, no deps) — before GEMM1's scatter fills valid cells
    zero_holes<1024, 114, +1><<<14080, 256, 0, stream>>>(xs);
    cvt_x<<<25088, 256, 0, stream>>>((const float4*)x, xb);
    prep_w<<<7168, 256, 0, stream>>>(fc_w, fc1_w, fc2_w, proj_w, fcwT, fc1T, fc2T, projT);

    // GEMM1: xh = gelu(xb@fc_w+b); dual store xh + fwd-shift scatter -> xs
    gemm_bt<1><<<dim3(8, 392), 256, 0, stream>>>(xb, fcwT, fc_b, xh, xs, nullptr, 1024, 512);
    // hs boundary holes (hs aliases xb -> must run after GEMM1)
    zero_holes<512, 57, -1><<<7040, 256, 0, stream>>>(hs);
    // GEMM2: hs = inv-shift scatter of gelu(xs@fc1_w+b); fused s0
    gemm_bt<2><<<dim3(4, 392), 256, 0, stream>>>(xs, fc1T, fc1_b, hs, nullptr, s0, 512, 1024);
    // GEMM3: w = gelu(xh@fc2_w+b) -> d_out (xs dead); fused s1
    gemm_bt<3><<<dim3(4, 392), 256, 0, stream>>>(xh, fc2T, fc2_b, wbuf, nullptr, s1, 512, 1024);
    // tiny MLP + softmax -> a0,a1
    tiny_mlp<<<1, 256, 0, stream>>>(s0, s1, rw1_w, rw1_b, rw2_w, rw2_b, a0, a1);
    // hw = hs*a0 + w*a1 -> xh region
    combine<<<12544, 256, 0, stream>>>((const uint4*)hs, (const uint4*)wbuf, a0, a1, (uint4*)hw);
    // GEMM4: out = hw @ proj_w + proj_b, fp32 -> d_out
    gemm_bt<0><<<dim3(4, 392), 256, 0, stream>>>(hw, projT, proj_b, d_out, nullptr, nullptr, 512, 512);
}